// Round 1
// baseline (3193.033 us; speedup 1.0000x reference)
//
#include <hip/hip_runtime.h>

#define NB 65536
#define NSTEP 128
#define HD 64
#define RB 1.05f

// tanh(x) = 1 - 2/(1+e^{2x}); accurate to ~few ulp, cheap (exp + rcp).
__device__ __forceinline__ float tanh_fast(float x) {
    float e2 = __expf(2.0f * x);
    return 1.0f - 2.0f * __builtin_amdgcn_rcpf(1.0f + e2);
}

__global__ __launch_bounds__(256) void sde_kernel(
    const float* __restrict__ xt0,
    const float* __restrict__ dBt,
    const float* __restrict__ W0u, const float* __restrict__ b0u,
    const float* __restrict__ W1u, const float* __restrict__ b1u,
    const float* __restrict__ W2u, const float* __restrict__ b2u,
    const float* __restrict__ Wg0, const float* __restrict__ bg0,
    const float* __restrict__ Wg1, const float* __restrict__ bg1,
    const float* __restrict__ Wg2, const float* __restrict__ bg2,
    float* __restrict__ out)
{
    const int b = blockIdx.x * blockDim.x + threadIdx.x;

    // state
    float xtx = xt0[b * 3 + 0];
    float xty = xt0[b * 3 + 1];
    float xtz = xt0[b * 3 + 2];
    float xix = xtx, xiy = xty, xiz = xtz;           // xt_in
    float g00 = 1.f, g01 = 0.f, g02 = 0.f;           // gt = I
    float g10 = 0.f, g11 = 1.f, g12 = 0.f;
    float g20 = 0.f, g21 = 0.f, g22 = 1.f;

    // ---- u_pre0 = fnn(xt0; Wu) ----
    float u_pre;
    {
        float h2[HD];
#pragma unroll
        for (int j = 0; j < HD; j++) h2[j] = b1u[j];
#pragma unroll 2
        for (int k = 0; k < HD; k++) {
            float a = fmaf(xtx, W0u[k], fmaf(xty, W0u[HD + k], fmaf(xtz, W0u[2 * HD + k], b0u[k])));
            float hk = tanh_fast(a);
            const float* wr = W1u + k * HD;
#pragma unroll
            for (int j = 0; j < HD; j++) h2[j] = fmaf(hk, wr[j], h2[j]);
        }
        float acc = b2u[0];
#pragma unroll
        for (int k = 0; k < HD; k++) acc = fmaf(tanh_fast(h2[k]), W2u[k], acc);
        u_pre = acc;
    }

    // ---- time loop ----
    for (int t = 0; t < NSTEP; t++) {
        // geometry from xt: Ti (t_inverse(theta - pi/2, phi)) without trig
        float r = sqrtf(fmaf(xtx, xtx, fmaf(xty, xty, xtz * xtz)));
        float uu = xtz / r;
        uu = fminf(fmaxf(uu, -0.999999f), 0.999999f);
        float ca = sqrtf((1.0f - uu) * (1.0f + uu)); // sin(theta) >= 0
        float sa = -uu;                              // -cos(theta)
        float rho = sqrtf(fmaf(xtx, xtx, xty * xty));
        float cp = (rho > 0.0f) ? (xtx / rho) : 1.0f;
        float sp = (rho > 0.0f) ? (xty / rho) : 0.0f;

        float T00 = cp * ca, T01 = -sp, T02 = cp * sa;
        float T10 = sp * ca, T11 = cp,  T12 = sp * sa;
        float T20 = -sa,               T22 = ca;     // T21 = 0

        // ---- MLP g = fnn(xt_in; step-t weights) ----
        const float* w0 = Wg0 + (size_t)t * 3 * HD;
        const float* c0 = bg0 + (size_t)t * HD;
        const float* w1 = Wg1 + (size_t)t * HD * HD;
        const float* c1 = bg1 + (size_t)t * HD;
        const float* w2 = Wg2 + (size_t)t * HD * 3;
        const float* c2 = bg2 + (size_t)t * 3;

        float h2[HD];
#pragma unroll
        for (int j = 0; j < HD; j++) h2[j] = c1[j];
#pragma unroll 2
        for (int k = 0; k < HD; k++) {
            float a = fmaf(xix, w0[k], fmaf(xiy, w0[HD + k], fmaf(xiz, w0[2 * HD + k], c0[k])));
            float hk = tanh_fast(a);
            const float* wr = w1 + k * HD;
#pragma unroll
            for (int j = 0; j < HD; j++) h2[j] = fmaf(hk, wr[j], h2[j]);
        }
        float gv0 = c2[0], gv1 = c2[1], gv2 = c2[2];
#pragma unroll
        for (int k = 0; k < HD; k++) {
            float hk = tanh_fast(h2[k]);
            gv0 = fmaf(hk, w2[3 * k + 0], gv0);
            gv1 = fmaf(hk, w2[3 * k + 1], gv1);
            gv2 = fmaf(hk, w2[3 * k + 2], gv2);
        }

        // v = g @ (gt @ Ti); need columns 1 and 2 only
        float M01 = fmaf(-sp, g00, cp * g01);
        float M11 = fmaf(-sp, g10, cp * g11);
        float M21 = fmaf(-sp, g20, cp * g21);
        float M02 = fmaf(g00, T02, fmaf(g01, T12, g02 * T22));
        float M12 = fmaf(g10, T02, fmaf(g11, T12, g12 * T22));
        float M22 = fmaf(g20, T02, fmaf(g21, T12, g22 * T22));
        float v1 = fmaf(gv0, M01, fmaf(gv1, M11, gv2 * M21));
        float v2 = fmaf(gv0, M02, fmaf(gv1, M12, gv2 * M22));

        float dB0 = dBt[(size_t)t * NB * 2 + (size_t)b * 2 + 0];
        float dB1 = dBt[(size_t)t * NB * 2 + (size_t)b * 2 + 1];

        // gu = (-v2, v1); u_pre += SQRT2D * (gu . dB), SQRT2D = 1
        u_pre += fmaf(v1, dB1, -v2 * dB0);

        // dX3: td = dB0 + pi/2 -> sin(td)=cos(dB0), cos(td)=-sin(dB0); pd = dB1
        float s0, c0d, s1, c1d;
        __sincosf(dB0, &s0, &c0d);
        __sincosf(dB1, &s1, &c1d);
        float dx30 = fmaf(c0d, c1d, -1.0f);
        float dx31 = c0d * s1;
        float dx32 = -s0;

        float dX0 = fmaf(T00, dx30, fmaf(T01, dx31, T02 * dx32));
        float dX1 = fmaf(T10, dx30, fmaf(T11, dx31, T12 * dx32));
        float dX2 = fmaf(T20, dx30, T22 * dx32);     // T21 = 0

        xtx += dX0; xty += dX1; xtz += dX2;

        // xi = xt_in + gt @ dX
        float xi0 = xix + fmaf(g00, dX0, fmaf(g01, dX1, g02 * dX2));
        float xi1 = xiy + fmaf(g10, dX0, fmaf(g11, dX1, g12 * dX2));
        float xi2 = xiz + fmaf(g20, dX0, fmaf(g21, dX1, g22 * dX2));

        float ri = sqrtf(fmaf(xi0, xi0, fmaf(xi1, xi1, xi2 * xi2)));
        bool outb = ri > RB;
        float n0 = xi0 / ri, n1 = xi1 / ri, n2 = xi2 / ri;
        float coef = 2.0f * (ri - RB);

        xix = outb ? fmaf(-coef, n0, xi0) : xi0;
        xiy = outb ? fmaf(-coef, n1, xi1) : xi1;
        xiz = outb ? fmaf(-coef, n2, xi2) : xi2;

        // m = n^T gt ; gt -= 2 n m^T (only when out)
        float m0 = fmaf(n0, g00, fmaf(n1, g10, n2 * g20));
        float m1 = fmaf(n0, g01, fmaf(n1, g11, n2 * g21));
        float m2 = fmaf(n0, g02, fmaf(n1, g12, n2 * g22));
        float tn0 = 2.0f * n0, tn1 = 2.0f * n1, tn2 = 2.0f * n2;
        g00 = outb ? fmaf(-tn0, m0, g00) : g00;
        g01 = outb ? fmaf(-tn0, m1, g01) : g01;
        g02 = outb ? fmaf(-tn0, m2, g02) : g02;
        g10 = outb ? fmaf(-tn1, m0, g10) : g10;
        g11 = outb ? fmaf(-tn1, m1, g11) : g11;
        g12 = outb ? fmaf(-tn1, m2, g12) : g12;
        g20 = outb ? fmaf(-tn2, m0, g20) : g20;
        g21 = outb ? fmaf(-tn2, m1, g21) : g21;
        g22 = outb ? fmaf(-tn2, m2, g22) : g22;
    }

    float u_rel = fmaf(xix, xix, fmaf(xiy, xiy, xiz * xiz));

    out[b] = u_pre;
    out[NB + b] = u_rel;
}

extern "C" void kernel_launch(void* const* d_in, const int* in_sizes, int n_in,
                              void* d_out, int out_size, void* d_ws, size_t ws_size,
                              hipStream_t stream) {
    const float* xt0 = (const float*)d_in[0];
    const float* dBt = (const float*)d_in[1];
    const float* W0u = (const float*)d_in[2];
    const float* b0u = (const float*)d_in[3];
    const float* W1u = (const float*)d_in[4];
    const float* b1u = (const float*)d_in[5];
    const float* W2u = (const float*)d_in[6];
    const float* b2u = (const float*)d_in[7];
    const float* Wg0 = (const float*)d_in[8];
    const float* bg0 = (const float*)d_in[9];
    const float* Wg1 = (const float*)d_in[10];
    const float* bg1 = (const float*)d_in[11];
    const float* Wg2 = (const float*)d_in[12];
    const float* bg2 = (const float*)d_in[13];
    float* out = (float*)d_out;

    dim3 grid(NB / 256), block(256);
    hipLaunchKernelGGL(sde_kernel, grid, block, 0, stream,
                       xt0, dBt, W0u, b0u, W1u, b1u, W2u, b2u,
                       Wg0, bg0, Wg1, bg1, Wg2, bg2, out);
}

// Round 2
// 786.527 us; speedup vs baseline: 4.0597x; 4.0597x over previous
//
#include <hip/hip_runtime.h>

#define NB 65536
#define NSTEP 128
#define HD 64
#define RB 1.05f

typedef __bf16 bf16x8 __attribute__((ext_vector_type(8)));
typedef float f32x16 __attribute__((ext_vector_type(16)));
typedef unsigned int uint;
typedef unsigned short ushort;

// tanh(x) = 1 - 2/(1+e^{2x})
__device__ __forceinline__ float tanh_fast(float x) {
    float e2 = __expf(2.0f * x);
    return 1.0f - 2.0f * __builtin_amdgcn_rcpf(1.0f + e2);
}

// pack two f32 -> (bf16(b)<<16)|bf16(a), truncation, single v_perm_b32
__device__ __forceinline__ uint pack_bf16_trunc(float a, float b) {
    return __builtin_amdgcn_perm(__float_as_uint(b), __float_as_uint(a), 0x07060302u);
}

__device__ __forceinline__ ushort bf16_rne(float f) {
    uint u = __float_as_uint(f);
    u += 0x7fffu + ((u >> 16) & 1u);
    return (ushort)(u >> 16);
}

// Pack Wg1 (N x 64 x 64 f32) into bf16 A-fragments for mfma_f32_32x32x16_bf16:
// blob[((t*4+kk)*2+I)*64 + lane] = 8 bf16: A[row=I*32+(lane&31)][k=kk*16+(lane>>5)*8+e]
// where A = W1^T, i.e. value = W1[k][row].
__global__ __launch_bounds__(256) void prep_kernel(const float* __restrict__ Wg1,
                                                   ushort* __restrict__ wsA) {
    int tid = blockIdx.x * 256 + threadIdx.x;   // ((t*4+kk)*2+I)*64 + lane
    int lane = tid & 63;
    int I    = (tid >> 6) & 1;
    int kk   = (tid >> 7) & 3;
    int t    = tid >> 9;
    int j  = I * 32 + (lane & 31);
    int k0 = kk * 16 + (lane >> 5) * 8;
    const float* src = Wg1 + ((size_t)t * HD + k0) * HD + j;
    ushort o[8];
#pragma unroll
    for (int e = 0; e < 8; e++) o[e] = bf16_rne(src[(size_t)e * HD]);
    uint4 v;
    v.x = (uint)o[0] | ((uint)o[1] << 16);
    v.y = (uint)o[2] | ((uint)o[3] << 16);
    v.z = (uint)o[4] | ((uint)o[5] << 16);
    v.w = (uint)o[6] | ((uint)o[7] << 16);
    ((uint4*)wsA)[tid] = v;
}

template <int PACKED>
__global__ __launch_bounds__(256) void sde_kernel(
    const float* __restrict__ xt0,
    const float* __restrict__ dBt,
    const float* __restrict__ W0u, const float* __restrict__ b0u,
    const float* __restrict__ W1u, const float* __restrict__ b1u,
    const float* __restrict__ W2u, const float* __restrict__ b2u,
    const float* __restrict__ Wg0, const float* __restrict__ bg0,
    const float* __restrict__ Wg1, const float* __restrict__ bg1,
    const float* __restrict__ Wg2, const float* __restrict__ bg2,
    const ushort* __restrict__ wsA,
    float* __restrict__ out)
{
    __shared__ ushort h1s[4 * HD * HD];   // 4 waves x 64 particles x 64 k (bf16), 32 KB

    const int tid  = threadIdx.x;
    const int lane = tid & 63;
    const int wv   = tid >> 6;
    const int b    = blockIdx.x * 256 + tid;
    const uint ldsBase = (uint)wv * 8192u;
    const int lh  = lane >> 5;
    const int l31 = lane & 31;

    // state
    float xtx = xt0[b * 3 + 0];
    float xty = xt0[b * 3 + 1];
    float xtz = xt0[b * 3 + 2];
    float xix = xtx, xiy = xty, xiz = xtz;
    float g00 = 1.f, g01 = 0.f, g02 = 0.f;
    float g10 = 0.f, g11 = 1.f, g12 = 0.f;
    float g20 = 0.f, g21 = 0.f, g22 = 1.f;

    // ---- u_pre0 = fnn(xt0; Wu) (runs once; scalar path) ----
    float u_pre;
    {
        float h2[HD];
#pragma unroll
        for (int j = 0; j < HD; j++) h2[j] = b1u[j];
#pragma unroll 2
        for (int k = 0; k < HD; k++) {
            float a = fmaf(xtx, W0u[k], fmaf(xty, W0u[HD + k], fmaf(xtz, W0u[2 * HD + k], b0u[k])));
            float hk = tanh_fast(a);
            const float* wr = W1u + k * HD;
#pragma unroll
            for (int j = 0; j < HD; j++) h2[j] = fmaf(hk, wr[j], h2[j]);
        }
        float acc = b2u[0];
#pragma unroll
        for (int k = 0; k < HD; k++) acc = fmaf(tanh_fast(h2[k]), W2u[k], acc);
        u_pre = acc;
    }

    // ---- time loop ----
#pragma unroll 1
    for (int t = 0; t < NSTEP; t++) {
        const float* w0 = Wg0 + (size_t)t * 3 * HD;
        const float* c0 = bg0 + (size_t)t * HD;
        const float* c1 = bg1 + (size_t)t * HD;
        const float* w2 = Wg2 + (size_t)t * HD * 3;
        const float* c2 = bg2 + (size_t)t * 3;

        // --- A fragments (W1^T bf16), wave-uniform data ---
        bf16x8 afrag[8];   // idx = kk*2 + I
        if (PACKED) {
            const uint4* base = (const uint4*)wsA + (size_t)t * 8 * 64 + lane;
#pragma unroll
            for (int f = 0; f < 8; f++)
                afrag[f] = __builtin_bit_cast(bf16x8, base[f * 64]);
        } else {
            const float* w1 = Wg1 + (size_t)t * HD * HD;
#pragma unroll
            for (int kk = 0; kk < 4; kk++)
#pragma unroll
            for (int I = 0; I < 2; I++) {
                uint pk[4];
#pragma unroll
                for (int ep = 0; ep < 4; ep++) {
                    float f0 = w1[(kk * 16 + lh * 8 + 2 * ep + 0) * HD + I * 32 + l31];
                    float f1 = w1[(kk * 16 + lh * 8 + 2 * ep + 1) * HD + I * 32 + l31];
                    pk[ep] = (uint)bf16_rne(f0) | ((uint)bf16_rne(f1) << 16);
                }
                uint4 v; v.x = pk[0]; v.y = pk[1]; v.z = pk[2]; v.w = pk[3];
                afrag[kk * 2 + I] = __builtin_bit_cast(bf16x8, v);
            }
        }

        // --- acc init = bias c1 in C layout (row=(r&3)+8*(r>>2)+4*lh + 32*I) ---
        f32x16 acc[2][2];   // [I][J]
#pragma unroll
        for (int I = 0; I < 2; I++) {
#pragma unroll
            for (int q = 0; q < 4; q++) {
                float4 bv = *(const float4*)(c1 + I * 32 + lh * 4 + 8 * q);
                acc[I][0][4 * q + 0] = bv.x; acc[I][0][4 * q + 1] = bv.y;
                acc[I][0][4 * q + 2] = bv.z; acc[I][0][4 * q + 3] = bv.w;
                acc[I][1][4 * q + 0] = bv.x; acc[I][1][4 * q + 1] = bv.y;
                acc[I][1][4 * q + 2] = bv.z; acc[I][1][4 * q + 3] = bv.w;
            }
        }

        // --- dB ---
        const float2 dB = *(const float2*)(dBt + ((size_t)t * NB + b) * 2);
        float dB0 = dB.x, dB1 = dB.y;

        // --- geometry (Ti without trig) ---
        float r = sqrtf(fmaf(xtx, xtx, fmaf(xty, xty, xtz * xtz)));
        float uu = xtz / r;
        uu = fminf(fmaxf(uu, -0.999999f), 0.999999f);
        float ca = sqrtf((1.0f - uu) * (1.0f + uu));
        float sa = -uu;
        float rho = sqrtf(fmaf(xtx, xtx, xty * xty));
        float cp = (rho > 0.0f) ? (xtx / rho) : 1.0f;
        float sp = (rho > 0.0f) ? (xty / rho) : 0.0f;
        float T00 = cp * ca, T01 = -sp, T02 = cp * sa;
        float T10 = sp * ca, T11 = cp,  T12 = sp * sa;
        float T20 = -sa,               T22 = ca;   // T21 = 0

        // --- layer 1: h1 = tanh(xt_in @ w0 + c0) -> bf16 -> LDS (swizzled rows) ---
#pragma unroll
        for (int c = 0; c < 8; c++) {
            uint pk[4];
#pragma unroll
            for (int p = 0; p < 4; p++) {
                int j0 = c * 8 + p * 2;
                float a0 = fmaf(xix, w0[j0],     fmaf(xiy, w0[HD + j0],     fmaf(xiz, w0[2 * HD + j0],     c0[j0])));
                float a1 = fmaf(xix, w0[j0 + 1], fmaf(xiy, w0[HD + j0 + 1], fmaf(xiz, w0[2 * HD + j0 + 1], c0[j0 + 1])));
                pk[p] = pack_bf16_trunc(tanh_fast(a0), tanh_fast(a1));
            }
            uint off = ldsBase + (uint)lane * 128u + ((16u * (uint)c) ^ (((uint)lane & 7u) << 4));
            uint4 v; v.x = pk[0]; v.y = pk[1]; v.z = pk[2]; v.w = pk[3];
            *(uint4*)((char*)h1s + off) = v;
        }

        // --- B fragments from LDS: B[k][p] = h1[p][k], p = J*32+l31, k = kk*16+lh*8+e ---
        bf16x8 bfrag[8];   // idx = kk*2 + J
#pragma unroll
        for (int kk = 0; kk < 4; kk++)
#pragma unroll
        for (int J = 0; J < 2; J++) {
            uint p  = (uint)(J * 32 + l31);
            uint ch = (uint)(kk * 2 + lh);
            uint off = ldsBase + p * 128u + ((16u * ch) ^ ((p & 7u) << 4));
            bfrag[kk * 2 + J] = *(bf16x8*)((char*)h1s + off);
        }

        // --- 16 MFMAs: acc[I][J] += A[I][kk] * B[J][kk] ---
#pragma unroll
        for (int kk = 0; kk < 4; kk++)
#pragma unroll
        for (int I = 0; I < 2; I++)
#pragma unroll
        for (int J = 0; J < 2; J++)
            acc[I][J] = __builtin_amdgcn_mfma_f32_32x32x16_bf16(
                afrag[kk * 2 + I], bfrag[kk * 2 + J], acc[I][J], 0, 0, 0);

        // --- layer 3: g partials over this lane's 32 rows for 2 particles ---
        float pj0c0 = 0.f, pj0c1 = 0.f, pj0c2 = 0.f;
        float pj1c0 = 0.f, pj1c1 = 0.f, pj1c2 = 0.f;
#pragma unroll
        for (int I = 0; I < 2; I++) {
#pragma unroll
            for (int q = 0; q < 4; q++) {
                int rb = I * 32 + 8 * q + lh * 4;        // global row of reg 4q
                const float* wp = w2 + 3 * rb;           // 12 consecutive floats
                float4 wa = *(const float4*)(wp);
                float4 wb = *(const float4*)(wp + 4);
                float4 wc = *(const float4*)(wp + 8);
                float wrow[4][3] = {{wa.x, wa.y, wa.z},
                                    {wa.w, wb.x, wb.y},
                                    {wb.z, wb.w, wc.x},
                                    {wc.y, wc.z, wc.w}};
#pragma unroll
                for (int j = 0; j < 4; j++) {
                    int rg = 4 * q + j;
                    float thA = tanh_fast(acc[I][0][rg]);
                    float thB = tanh_fast(acc[I][1][rg]);
                    pj0c0 = fmaf(thA, wrow[j][0], pj0c0);
                    pj0c1 = fmaf(thA, wrow[j][1], pj0c1);
                    pj0c2 = fmaf(thA, wrow[j][2], pj0c2);
                    pj1c0 = fmaf(thB, wrow[j][0], pj1c0);
                    pj1c1 = fmaf(thB, wrow[j][1], pj1c1);
                    pj1c2 = fmaf(thB, wrow[j][2], pj1c2);
                }
            }
        }
        // combine halves: my particle's other-half partial lives in lane^32
        bool lo = (lane < 32);
        float m0 = lo ? pj0c0 : pj1c0, s0v = lo ? pj1c0 : pj0c0;
        float m1 = lo ? pj0c1 : pj1c1, s1v = lo ? pj1c1 : pj0c1;
        float m2 = lo ? pj0c2 : pj1c2, s2v = lo ? pj1c2 : pj0c2;
        float gv0 = m0 + __shfl_xor(s0v, 32, 64) + c2[0];
        float gv1 = m1 + __shfl_xor(s1v, 32, 64) + c2[1];
        float gv2 = m2 + __shfl_xor(s2v, 32, 64) + c2[2];

        // --- v = g @ (gt @ Ti), columns 1,2 only ---
        float M01 = fmaf(-sp, g00, cp * g01);
        float M11 = fmaf(-sp, g10, cp * g11);
        float M21 = fmaf(-sp, g20, cp * g21);
        float M02 = fmaf(g00, T02, fmaf(g01, T12, g02 * T22));
        float M12 = fmaf(g10, T02, fmaf(g11, T12, g12 * T22));
        float M22 = fmaf(g20, T02, fmaf(g21, T12, g22 * T22));
        float v1 = fmaf(gv0, M01, fmaf(gv1, M11, gv2 * M21));
        float v2 = fmaf(gv0, M02, fmaf(gv1, M12, gv2 * M22));

        u_pre += fmaf(v1, dB1, -v2 * dB0);

        // --- dX3 / dX ---
        float s0d, c0d, s1d, c1d;
        __sincosf(dB0, &s0d, &c0d);
        __sincosf(dB1, &s1d, &c1d);
        float dx30 = fmaf(c0d, c1d, -1.0f);
        float dx31 = c0d * s1d;
        float dx32 = -s0d;

        float dX0 = fmaf(T00, dx30, fmaf(T01, dx31, T02 * dx32));
        float dX1 = fmaf(T10, dx30, fmaf(T11, dx31, T12 * dx32));
        float dX2 = fmaf(T20, dx30, T22 * dx32);

        xtx += dX0; xty += dX1; xtz += dX2;

        float xi0 = xix + fmaf(g00, dX0, fmaf(g01, dX1, g02 * dX2));
        float xi1 = xiy + fmaf(g10, dX0, fmaf(g11, dX1, g12 * dX2));
        float xi2 = xiz + fmaf(g20, dX0, fmaf(g21, dX1, g22 * dX2));

        float ri = sqrtf(fmaf(xi0, xi0, fmaf(xi1, xi1, xi2 * xi2)));
        bool outb = ri > RB;
        float n0 = xi0 / ri, n1 = xi1 / ri, n2 = xi2 / ri;
        float coef = 2.0f * (ri - RB);

        xix = outb ? fmaf(-coef, n0, xi0) : xi0;
        xiy = outb ? fmaf(-coef, n1, xi1) : xi1;
        xiz = outb ? fmaf(-coef, n2, xi2) : xi2;

        float mm0 = fmaf(n0, g00, fmaf(n1, g10, n2 * g20));
        float mm1 = fmaf(n0, g01, fmaf(n1, g11, n2 * g21));
        float mm2 = fmaf(n0, g02, fmaf(n1, g12, n2 * g22));
        float tn0 = 2.0f * n0, tn1 = 2.0f * n1, tn2 = 2.0f * n2;
        g00 = outb ? fmaf(-tn0, mm0, g00) : g00;
        g01 = outb ? fmaf(-tn0, mm1, g01) : g01;
        g02 = outb ? fmaf(-tn0, mm2, g02) : g02;
        g10 = outb ? fmaf(-tn1, mm0, g10) : g10;
        g11 = outb ? fmaf(-tn1, mm1, g11) : g11;
        g12 = outb ? fmaf(-tn1, mm2, g12) : g12;
        g20 = outb ? fmaf(-tn2, mm0, g20) : g20;
        g21 = outb ? fmaf(-tn2, mm1, g21) : g21;
        g22 = outb ? fmaf(-tn2, mm2, g22) : g22;
    }

    float u_rel = fmaf(xix, xix, fmaf(xiy, xiy, xiz * xiz));
    out[b] = u_pre;
    out[NB + b] = u_rel;
}

extern "C" void kernel_launch(void* const* d_in, const int* in_sizes, int n_in,
                              void* d_out, int out_size, void* d_ws, size_t ws_size,
                              hipStream_t stream) {
    const float* xt0 = (const float*)d_in[0];
    const float* dBt = (const float*)d_in[1];
    const float* W0u = (const float*)d_in[2];
    const float* b0u = (const float*)d_in[3];
    const float* W1u = (const float*)d_in[4];
    const float* b1u = (const float*)d_in[5];
    const float* W2u = (const float*)d_in[6];
    const float* b2u = (const float*)d_in[7];
    const float* Wg0 = (const float*)d_in[8];
    const float* bg0 = (const float*)d_in[9];
    const float* Wg1 = (const float*)d_in[10];
    const float* bg1 = (const float*)d_in[11];
    const float* Wg2 = (const float*)d_in[12];
    const float* bg2 = (const float*)d_in[13];
    float* out = (float*)d_out;

    const size_t needed = (size_t)NSTEP * 4 * 2 * 64 * 8 * sizeof(ushort);  // 1 MB
    dim3 grid(NB / 256), block(256);
    if (ws_size >= needed && d_ws != nullptr) {
        hipLaunchKernelGGL(prep_kernel, dim3(256), dim3(256), 0, stream, Wg1, (ushort*)d_ws);
        hipLaunchKernelGGL((sde_kernel<1>), grid, block, 0, stream,
                           xt0, dBt, W0u, b0u, W1u, b1u, W2u, b2u,
                           Wg0, bg0, Wg1, bg1, Wg2, bg2, (const ushort*)d_ws, out);
    } else {
        hipLaunchKernelGGL((sde_kernel<0>), grid, block, 0, stream,
                           xt0, dBt, W0u, b0u, W1u, b1u, W2u, b2u,
                           Wg0, bg0, Wg1, bg1, Wg2, bg2, (const ushort*)nullptr, out);
    }
}

// Round 3
// 677.055 us; speedup vs baseline: 4.7161x; 1.1617x over previous
//
#include <hip/hip_runtime.h>

#define NB 65536
#define NSTEP 128
#define HD 64
#define RB 1.05f

typedef __bf16 bf16x8 __attribute__((ext_vector_type(8)));
typedef float f32x4 __attribute__((ext_vector_type(4)));
typedef unsigned int uint;
typedef unsigned short ushort;

// tanh(x) = 1 - 2/(1+e^{2x})
__device__ __forceinline__ float tanh_fast(float x) {
    float e2 = __expf(2.0f * x);
    return 1.0f - 2.0f * __builtin_amdgcn_rcpf(1.0f + e2);
}

// pack two f32 -> (bf16(b)<<16)|bf16(a), truncation, single v_perm_b32
__device__ __forceinline__ uint pack_bf16_trunc(float a, float b) {
    return __builtin_amdgcn_perm(__float_as_uint(b), __float_as_uint(a), 0x07060302u);
}

__device__ __forceinline__ ushort bf16_rne(float f) {
    uint u = __float_as_uint(f);
    u += 0x7fffu + ((u >> 16) & 1u);
    return (ushort)(u >> 16);
}

// Pack Wg1 (N x 64 x 64 f32) into bf16 A-fragments for mfma_f32_16x16x32_bf16.
// A = W1^T (A[row][k] = W1[k][row]).  Fragment layout (16x16x32 family):
//   lane holds A[row = I*16 + (lane&15)][k = kk*32 + (lane>>4)*8 + e], e=0..7
// blob index: wsA[((t*2+kk)*4+I)*64 + lane]  (uint4 = 8 bf16)
__global__ __launch_bounds__(256) void prep_kernel(const float* __restrict__ Wg1,
                                                   uint4* __restrict__ wsA) {
    int tid  = blockIdx.x * 256 + threadIdx.x;
    int lane = tid & 63;
    int I    = (tid >> 6) & 3;
    int kk   = (tid >> 8) & 1;
    int t    = tid >> 9;
    int row  = I * 16 + (lane & 15);
    int k0   = kk * 32 + ((lane >> 4) & 3) * 8;
    const float* src = Wg1 + ((size_t)t * HD + k0) * HD + row;
    ushort o[8];
#pragma unroll
    for (int e = 0; e < 8; e++) o[e] = bf16_rne(src[(size_t)e * HD]);
    uint4 v;
    v.x = (uint)o[0] | ((uint)o[1] << 16);
    v.y = (uint)o[2] | ((uint)o[3] << 16);
    v.z = (uint)o[4] | ((uint)o[5] << 16);
    v.w = (uint)o[6] | ((uint)o[7] << 16);
    wsA[tid] = v;
}

// h2 (pre-bias) for this wave's 16 particles: acc[I][r] = h2[row=I*16+g16*4+r] of
// particle p=lane&15.  A from packed blob (PACKED) or strided gather of w1 (else).
template <int PACKED>
__device__ __forceinline__ void mlp_h2(float xx, float xy, float xz,
                                       const float* __restrict__ w0,
                                       const float* __restrict__ c0,
                                       const uint4* __restrict__ apk,
                                       const float* __restrict__ w1,
                                       int lane, f32x4* acc) {
    const int g16 = (lane >> 4) & 3;
    const int l15 = lane & 15;
#pragma unroll
    for (int kk = 0; kk < 2; kk++) {
        // --- A fragments (4 row tiles) ---
        bf16x8 af[4];
        if (PACKED) {
            const uint4* bp = apk + kk * 256 + lane;
#pragma unroll
            for (int I = 0; I < 4; I++) af[I] = __builtin_bit_cast(bf16x8, bp[I * 64]);
        } else {
#pragma unroll
            for (int I = 0; I < 4; I++) {
                uint pk[4];
#pragma unroll
                for (int ep = 0; ep < 4; ep++) {
                    float f0 = w1[(kk * 32 + g16 * 8 + 2 * ep + 0) * HD + I * 16 + l15];
                    float f1 = w1[(kk * 32 + g16 * 8 + 2 * ep + 1) * HD + I * 16 + l15];
                    pk[ep] = (uint)bf16_rne(f0) | ((uint)bf16_rne(f1) << 16);
                }
                uint4 v; v.x = pk[0]; v.y = pk[1]; v.z = pk[2]; v.w = pk[3];
                af[I] = __builtin_bit_cast(bf16x8, v);
            }
        }
        // --- B fragment: h1[p][k], k = kk*32 + g16*8 + e (this lane's slice) ---
        const float* wk = w0 + kk * 32 + g16 * 8;
        float4 wxa = *(const float4*)(wk);
        float4 wxb = *(const float4*)(wk + 4);
        float4 wya = *(const float4*)(wk + HD);
        float4 wyb = *(const float4*)(wk + HD + 4);
        float4 wza = *(const float4*)(wk + 2 * HD);
        float4 wzb = *(const float4*)(wk + 2 * HD + 4);
        const float* ck = c0 + kk * 32 + g16 * 8;
        float4 cva = *(const float4*)(ck);
        float4 cvb = *(const float4*)(ck + 4);
        float p0 = fmaf(xx, wxa.x, fmaf(xy, wya.x, fmaf(xz, wza.x, cva.x)));
        float p1 = fmaf(xx, wxa.y, fmaf(xy, wya.y, fmaf(xz, wza.y, cva.y)));
        float p2 = fmaf(xx, wxa.z, fmaf(xy, wya.z, fmaf(xz, wza.z, cva.z)));
        float p3 = fmaf(xx, wxa.w, fmaf(xy, wya.w, fmaf(xz, wza.w, cva.w)));
        float p4 = fmaf(xx, wxb.x, fmaf(xy, wyb.x, fmaf(xz, wzb.x, cvb.x)));
        float p5 = fmaf(xx, wxb.y, fmaf(xy, wyb.y, fmaf(xz, wzb.y, cvb.y)));
        float p6 = fmaf(xx, wxb.z, fmaf(xy, wyb.z, fmaf(xz, wzb.z, cvb.z)));
        float p7 = fmaf(xx, wxb.w, fmaf(xy, wyb.w, fmaf(xz, wzb.w, cvb.w)));
        uint4 bv;
        bv.x = pack_bf16_trunc(tanh_fast(p0), tanh_fast(p1));
        bv.y = pack_bf16_trunc(tanh_fast(p2), tanh_fast(p3));
        bv.z = pack_bf16_trunc(tanh_fast(p4), tanh_fast(p5));
        bv.w = pack_bf16_trunc(tanh_fast(p6), tanh_fast(p7));
        bf16x8 bf = __builtin_bit_cast(bf16x8, bv);
#pragma unroll
        for (int I = 0; I < 4; I++)
            acc[I] = __builtin_amdgcn_mfma_f32_16x16x32_bf16(af[I], bf, acc[I], 0, 0, 0);
    }
}

template <int PACKED>
__global__ __launch_bounds__(256, 4) void sde_kernel(
    const float* __restrict__ xt0,
    const float* __restrict__ dBt,
    const float* __restrict__ W0u, const float* __restrict__ b0u,
    const float* __restrict__ W1u, const float* __restrict__ b1u,
    const float* __restrict__ W2u, const float* __restrict__ b2u,
    const float* __restrict__ Wg0, const float* __restrict__ bg0,
    const float* __restrict__ Wg1, const float* __restrict__ bg1,
    const float* __restrict__ Wg2, const float* __restrict__ bg2,
    const uint4* __restrict__ wsA,
    float* __restrict__ out)
{
    const int tid  = threadIdx.x;
    const int lane = tid & 63;
    const int wv   = tid >> 6;
    const int g16  = (lane >> 4) & 3;
    const int l15  = lane & 15;
    const int p    = blockIdx.x * 64 + wv * 16 + l15;   // particle id (4 lanes share)

    // state (replicated across the particle's 4 lanes; identical arithmetic)
    float xtx = xt0[p * 3 + 0];
    float xty = xt0[p * 3 + 1];
    float xtz = xt0[p * 3 + 2];
    float xix = xtx, xiy = xty, xiz = xtz;
    float g00 = 1.f, g01 = 0.f, g02 = 0.f;
    float g10 = 0.f, g11 = 1.f, g12 = 0.f;
    float g20 = 0.f, g21 = 0.f, g22 = 1.f;

    // ---- u_pre0 = fnn(xt0; Wu) via the same MFMA machinery ----
    float u_pre;
    {
        f32x4 acc[4];
#pragma unroll
        for (int I = 0; I < 4; I++) acc[I] = (f32x4){0.f, 0.f, 0.f, 0.f};
        mlp_h2<0>(xtx, xty, xtz, W0u, b0u, nullptr, W1u, lane, acc);
        float pj = 0.f;
#pragma unroll
        for (int I = 0; I < 4; I++) {
            float4 wv2 = *(const float4*)(W2u + I * 16 + g16 * 4);
            float4 cv  = *(const float4*)(b1u + I * 16 + g16 * 4);
            pj = fmaf(tanh_fast(acc[I][0] + cv.x), wv2.x, pj);
            pj = fmaf(tanh_fast(acc[I][1] + cv.y), wv2.y, pj);
            pj = fmaf(tanh_fast(acc[I][2] + cv.z), wv2.z, pj);
            pj = fmaf(tanh_fast(acc[I][3] + cv.w), wv2.w, pj);
        }
        pj += __shfl_xor(pj, 16, 64);
        pj += __shfl_xor(pj, 32, 64);
        u_pre = pj + b2u[0];
    }

    // ---- time loop ----
#pragma unroll 1
    for (int t = 0; t < NSTEP; t++) {
        const float* w0 = Wg0 + (size_t)t * 3 * HD;
        const float* c0 = bg0 + (size_t)t * HD;
        const float* c1 = bg1 + (size_t)t * HD;
        const float* w2 = Wg2 + (size_t)t * HD * 3;
        const float* c2 = bg2 + (size_t)t * 3;

        // --- geometry (Ti without trig) ---
        float r = sqrtf(fmaf(xtx, xtx, fmaf(xty, xty, xtz * xtz)));
        float uu = xtz / r;
        uu = fminf(fmaxf(uu, -0.999999f), 0.999999f);
        float ca = sqrtf((1.0f - uu) * (1.0f + uu));
        float sa = -uu;
        float rho = sqrtf(fmaf(xtx, xtx, xty * xty));
        float cp = (rho > 0.0f) ? (xtx / rho) : 1.0f;
        float sp = (rho > 0.0f) ? (xty / rho) : 0.0f;
        float T00 = cp * ca, T01 = -sp, T02 = cp * sa;
        float T10 = sp * ca, T11 = cp,  T12 = sp * sa;
        float T20 = -sa,               T22 = ca;   // T21 = 0

        // --- MLP: h2 via MFMA (no LDS; B-frag == this lane's h1 slice) ---
        f32x4 acc[4];
#pragma unroll
        for (int I = 0; I < 4; I++) acc[I] = (f32x4){0.f, 0.f, 0.f, 0.f};
        mlp_h2<PACKED>(xix, xiy, xiz, w0, c0,
                       PACKED ? (wsA + (size_t)t * 512) : nullptr,
                       Wg1 + (size_t)t * HD * HD, lane, acc);

        // --- layer 3: partials over this lane's 16 rows ---
        float pj0 = 0.f, pj1 = 0.f, pj2 = 0.f;
#pragma unroll
        for (int I = 0; I < 4; I++) {
            const float* wp = w2 + 3 * (I * 16 + g16 * 4);   // 12 contiguous floats
            float4 wa = *(const float4*)(wp);
            float4 wb = *(const float4*)(wp + 4);
            float4 wc = *(const float4*)(wp + 8);
            float4 cv = *(const float4*)(c1 + I * 16 + g16 * 4);
            float th0 = tanh_fast(acc[I][0] + cv.x);
            float th1 = tanh_fast(acc[I][1] + cv.y);
            float th2 = tanh_fast(acc[I][2] + cv.z);
            float th3 = tanh_fast(acc[I][3] + cv.w);
            pj0 = fmaf(th0, wa.x, pj0); pj1 = fmaf(th0, wa.y, pj1); pj2 = fmaf(th0, wa.z, pj2);
            pj0 = fmaf(th1, wa.w, pj0); pj1 = fmaf(th1, wb.x, pj1); pj2 = fmaf(th1, wb.y, pj2);
            pj0 = fmaf(th2, wb.z, pj0); pj1 = fmaf(th2, wb.w, pj1); pj2 = fmaf(th2, wc.x, pj2);
            pj0 = fmaf(th3, wc.y, pj0); pj1 = fmaf(th3, wc.z, pj1); pj2 = fmaf(th3, wc.w, pj2);
        }
        pj0 += __shfl_xor(pj0, 16, 64); pj0 += __shfl_xor(pj0, 32, 64);
        pj1 += __shfl_xor(pj1, 16, 64); pj1 += __shfl_xor(pj1, 32, 64);
        pj2 += __shfl_xor(pj2, 16, 64); pj2 += __shfl_xor(pj2, 32, 64);
        float gv0 = pj0 + c2[0];
        float gv1 = pj1 + c2[1];
        float gv2 = pj2 + c2[2];

        // --- v = g @ (gt @ Ti), columns 1,2 only ---
        float M01 = fmaf(-sp, g00, cp * g01);
        float M11 = fmaf(-sp, g10, cp * g11);
        float M21 = fmaf(-sp, g20, cp * g21);
        float M02 = fmaf(g00, T02, fmaf(g01, T12, g02 * T22));
        float M12 = fmaf(g10, T02, fmaf(g11, T12, g12 * T22));
        float M22 = fmaf(g20, T02, fmaf(g21, T12, g22 * T22));
        float v1 = fmaf(gv0, M01, fmaf(gv1, M11, gv2 * M21));
        float v2 = fmaf(gv0, M02, fmaf(gv1, M12, gv2 * M22));

        const float2 dB = *(const float2*)(dBt + ((size_t)t * NB + p) * 2);
        float dB0 = dB.x, dB1 = dB.y;

        u_pre += fmaf(v1, dB1, -v2 * dB0);

        // --- dX3 / dX ---
        float s0d, c0d, s1d, c1d;
        __sincosf(dB0, &s0d, &c0d);
        __sincosf(dB1, &s1d, &c1d);
        float dx30 = fmaf(c0d, c1d, -1.0f);
        float dx31 = c0d * s1d;
        float dx32 = -s0d;

        float dX0 = fmaf(T00, dx30, fmaf(T01, dx31, T02 * dx32));
        float dX1 = fmaf(T10, dx30, fmaf(T11, dx31, T12 * dx32));
        float dX2 = fmaf(T20, dx30, T22 * dx32);

        xtx += dX0; xty += dX1; xtz += dX2;

        float xi0 = xix + fmaf(g00, dX0, fmaf(g01, dX1, g02 * dX2));
        float xi1 = xiy + fmaf(g10, dX0, fmaf(g11, dX1, g12 * dX2));
        float xi2 = xiz + fmaf(g20, dX0, fmaf(g21, dX1, g22 * dX2));

        float ri = sqrtf(fmaf(xi0, xi0, fmaf(xi1, xi1, xi2 * xi2)));
        bool outb = ri > RB;
        float n0 = xi0 / ri, n1 = xi1 / ri, n2 = xi2 / ri;
        float coef = 2.0f * (ri - RB);

        xix = outb ? fmaf(-coef, n0, xi0) : xi0;
        xiy = outb ? fmaf(-coef, n1, xi1) : xi1;
        xiz = outb ? fmaf(-coef, n2, xi2) : xi2;

        float mm0 = fmaf(n0, g00, fmaf(n1, g10, n2 * g20));
        float mm1 = fmaf(n0, g01, fmaf(n1, g11, n2 * g21));
        float mm2 = fmaf(n0, g02, fmaf(n1, g12, n2 * g22));
        float tn0 = 2.0f * n0, tn1 = 2.0f * n1, tn2 = 2.0f * n2;
        g00 = outb ? fmaf(-tn0, mm0, g00) : g00;
        g01 = outb ? fmaf(-tn0, mm1, g01) : g01;
        g02 = outb ? fmaf(-tn0, mm2, g02) : g02;
        g10 = outb ? fmaf(-tn1, mm0, g10) : g10;
        g11 = outb ? fmaf(-tn1, mm1, g11) : g11;
        g12 = outb ? fmaf(-tn1, mm2, g12) : g12;
        g20 = outb ? fmaf(-tn2, mm0, g20) : g20;
        g21 = outb ? fmaf(-tn2, mm1, g21) : g21;
        g22 = outb ? fmaf(-tn2, mm2, g22) : g22;
    }

    float u_rel = fmaf(xix, xix, fmaf(xiy, xiy, xiz * xiz));
    if (g16 == 0) {
        out[p] = u_pre;
        out[NB + p] = u_rel;
    }
}

extern "C" void kernel_launch(void* const* d_in, const int* in_sizes, int n_in,
                              void* d_out, int out_size, void* d_ws, size_t ws_size,
                              hipStream_t stream) {
    const float* xt0 = (const float*)d_in[0];
    const float* dBt = (const float*)d_in[1];
    const float* W0u = (const float*)d_in[2];
    const float* b0u = (const float*)d_in[3];
    const float* W1u = (const float*)d_in[4];
    const float* b1u = (const float*)d_in[5];
    const float* W2u = (const float*)d_in[6];
    const float* b2u = (const float*)d_in[7];
    const float* Wg0 = (const float*)d_in[8];
    const float* bg0 = (const float*)d_in[9];
    const float* Wg1 = (const float*)d_in[10];
    const float* bg1 = (const float*)d_in[11];
    const float* Wg2 = (const float*)d_in[12];
    const float* bg2 = (const float*)d_in[13];
    float* out = (float*)d_out;

    const size_t needed = (size_t)NSTEP * 2 * 4 * 64 * sizeof(uint4);  // 1 MB
    dim3 grid(NB * 4 / 256), block(256);   // 16 particles per wave -> 4096 waves
    if (ws_size >= needed && d_ws != nullptr) {
        hipLaunchKernelGGL(prep_kernel, dim3(256), dim3(256), 0, stream, Wg1, (uint4*)d_ws);
        hipLaunchKernelGGL((sde_kernel<1>), grid, block, 0, stream,
                           xt0, dBt, W0u, b0u, W1u, b1u, W2u, b2u,
                           Wg0, bg0, Wg1, bg1, Wg2, bg2, (const uint4*)d_ws, out);
    } else {
        hipLaunchKernelGGL((sde_kernel<0>), grid, block, 0, stream,
                           xt0, dBt, W0u, b0u, W1u, b1u, W2u, b2u,
                           Wg0, bg0, Wg1, bg1, Wg2, bg2, (const uint4*)nullptr, out);
    }
}